// Round 5
// baseline (314.639 us; speedup 1.0000x reference)
//
#include <hip/hip_runtime.h>

// Maxwell RNN scan: gamma_n = (1-h_n) gamma_{n-1} + h_n eps_n, h = 0.5*dt
// sig_n = 2.5*eps_n - gamma_{n-1}   (pre-update gamma)
//
// Persistent-streaming version: 256-thread blocks (4-wave barriers, 8
// independent blocks/CU for burst phase-diversity), each block owns 2
// consecutive rows = 8 sequential 2048-elem tiles over a contiguous 64 KB
// region. A DEPTH-2 register ring keeps the loads for tile t+2 in flight
// while tile t is scanned/replayed -- the memory pipe never drains (the
// failure mode of R0-R4, which all issued synchronized bursts and idled
// the pipe ~90% of the time at 4.8 TB/s delivered vs 6.3 achievable).
// Parity-double-buffered wA/wB: ONE barrier per tile (t+1's barrier covers
// the t+2 WAR hazard). Plain stores (NT stores amplify HBM writes 1.5-2.6x).

constexpr int   T_LEN   = 8192;
constexpr int   THREADS = 256;
constexpr int   V       = 8;
constexpr int   TILE    = THREADS * V;    // 2048
constexpr int   TPR     = T_LEN / TILE;   // 4 tiles per row
constexpr int   ROWS_PB = 2;              // rows per block
constexpr int   NT      = ROWS_PB * TPR;  // 8 tiles per block
constexpr int   NWAVES  = THREADS / 64;   // 4
constexpr float KCOEF   = 0.5f;           // E_MOD / ETA

typedef float f32x4 __attribute__((ext_vector_type(4)));

__global__ __launch_bounds__(THREADS) void maxwell_scan_kernel(
    const float* __restrict__ eps, const float* __restrict__ dtv,
    float* __restrict__ out)
{
    const int tid  = threadIdx.x;
    const int lane = tid & 63;
    const int wid  = tid >> 6;

    __shared__ float wA[2][NWAVES], wB[2][NWAVES];

    const size_t base0 = (size_t)blockIdx.x * (ROWS_PB * T_LEN) + (size_t)tid * V;
    const float* ep = eps + base0;
    const float* dp = dtv + base0;
    float*       op = out + base0;

    // ---- DEPTH-2 register ring (named slots -> fully static indexing).
    f32x4 be0_0 = *(const f32x4*)(ep);
    f32x4 be1_0 = *(const f32x4*)(ep + 4);
    f32x4 bd0_0 = *(const f32x4*)(dp);
    f32x4 bd1_0 = *(const f32x4*)(dp + 4);
    f32x4 be0_1 = *(const f32x4*)(ep + TILE);
    f32x4 be1_1 = *(const f32x4*)(ep + TILE + 4);
    f32x4 bd0_1 = *(const f32x4*)(dp + TILE);
    f32x4 bd1_1 = *(const f32x4*)(dp + TILE + 4);

    float gamma = 0.0f;

    #pragma unroll 2   // makes p = t&1 compile-time: ring slots stay in regs
    for (int t = 0; t < NT; ++t) {
        const int p = t & 1;
        if ((t & (TPR - 1)) == 0) gamma = 0.0f;   // row boundary: reset carry

        // ---- Consume ring slot p into locals (vmcnt wait lands here; the
        // other slot's 4 loads stay in flight).
        f32x4 E0 = p ? be0_1 : be0_0;
        f32x4 E1 = p ? be1_1 : be1_0;
        f32x4 D0 = p ? bd0_1 : bd0_0;
        f32x4 D1 = p ? bd1_1 : bd1_0;

        // ---- Immediately refill slot p with tile t+2: keeps 8 loads/thread
        // in flight through the whole scan/barrier/replay phase.
        if (t + 2 < NT) {
            const float* epn = ep + (size_t)(t + 2) * TILE;
            const float* dpn = dp + (size_t)(t + 2) * TILE;
            if (p) {
                be0_1 = *(const f32x4*)(epn);
                be1_1 = *(const f32x4*)(epn + 4);
                bd0_1 = *(const f32x4*)(dpn);
                bd1_1 = *(const f32x4*)(dpn + 4);
            } else {
                be0_0 = *(const f32x4*)(epn);
                be1_0 = *(const f32x4*)(epn + 4);
                bd0_0 = *(const f32x4*)(dpn);
                bd1_0 = *(const f32x4*)(dpn + 4);
            }
        }

        float ev[V] = {E0.x, E0.y, E0.z, E0.w, E1.x, E1.y, E1.z, E1.w};
        float hv[V] = {D0.x * KCOEF, D0.y * KCOEF, D0.z * KCOEF, D0.w * KCOEF,
                       D1.x * KCOEF, D1.y * KCOEF, D1.z * KCOEF, D1.w * KCOEF};

        // ---- Compose this thread's chunk: gamma_out = A*gamma_in + B.
        float A = 1.0f, Bc = 0.0f;
        #pragma unroll
        for (int j = 0; j < V; ++j) {
            float a = 1.0f - hv[j];
            Bc = a * Bc + hv[j] * ev[j];
            A *= a;
        }

        // ---- Inclusive wave scan under composition (later ∘ earlier).
        float sa = A, sb = Bc;
        #pragma unroll
        for (int off = 1; off < 64; off <<= 1) {
            float pa = __shfl_up(sa, off, 64);
            float pb = __shfl_up(sb, off, 64);
            if (lane >= off) {
                sb = sa * pb + sb;
                sa = sa * pa;
            }
        }
        if (lane == 63) { wA[p][wid] = sa; wB[p][wid] = sb; }
        __syncthreads();   // the ONLY barrier per tile (parity ring covers WAR)

        // ---- Exclusive-within-wave transform.
        float xa = __shfl_up(sa, 1, 64);
        float xb = __shfl_up(sb, 1, 64);
        if (lane == 0) { xa = 1.0f; xb = 0.0f; }

        // ---- Prefix over preceding waves (pfa,pfb) and block total (ta,tb).
        float pfa = 1.0f, pfb = 0.0f;
        float ta  = 1.0f, tb  = 0.0f;
        #pragma unroll
        for (int w = 0; w < NWAVES; ++w) {
            float a = wA[p][w], bb = wB[p][w];
            if (w < wid) { pfb = a * pfb + bb; pfa *= a; }
            tb = a * tb + bb;
            ta *= a;
        }

        // Thread's exclusive block transform applied to tile-entering gamma.
        float ga = xa * pfa;
        float gb = xa * pfb + xb;
        float g  = ga * gamma + gb;

        // ---- Replay: emit sigma, advance gamma. Plain stores.
        float* opn = op + (size_t)t * TILE;
        f32x4 sg;
        #pragma unroll
        for (int j = 0; j < 4; ++j) {
            sg[j] = 2.5f * ev[j] - g;           // E_INF*e + E*(e - g)
            g = g + hv[j] * (ev[j] - g);        // g += dt*k*(e - g)
        }
        *(f32x4*)(opn) = sg;
        #pragma unroll
        for (int j = 0; j < 4; ++j) {
            sg[j] = 2.5f * ev[4 + j] - g;
            g = g + hv[4 + j] * (ev[4 + j] - g);
        }
        *(f32x4*)(opn + 4) = sg;

        // ---- Advance carry by the block-total transform (uniform).
        gamma = ta * gamma + tb;
    }
}

extern "C" void kernel_launch(void* const* d_in, const int* in_sizes, int n_in,
                              void* d_out, int out_size, void* d_ws, size_t ws_size,
                              hipStream_t stream) {
    const float* eps = (const float*)d_in[0];
    const float* dtv = (const float*)d_in[1];
    float* out = (float*)d_out;
    const int B = in_sizes[0] / T_LEN;        // 4096 rows
    const int blocks = B / ROWS_PB;           // 2048 blocks (8/CU resident)
    maxwell_scan_kernel<<<blocks, THREADS, 0, stream>>>(eps, dtv, out);
}

// Round 6
// 307.459 us; speedup vs baseline: 1.0234x; 1.0234x over previous
//
#include <hip/hip_runtime.h>

// Maxwell RNN scan: gamma_n = (1-h_n) gamma_{n-1} + h_n eps_n, h = 0.5*dt
// sig_n = 2.5*eps_n - gamma_{n-1}   (pre-update gamma)
//
// R6: FULL-DENSITY memory instructions. Thread t owns elems [4t, 4t+4) of a
// 1024-elem tile -> every global load/store instruction has lane-stride
// exactly 16B (16 cache lines per wave-instruction, the minimum). All
// previous variants used per-thread V=8 chunks = 50% density = 2x the
// line-transactions per useful byte on both loads and stores.
// Plus: 256-thr blocks, one row per block (grid 4096 = 16 blocks/CU for
// backfill), parity-buffered wA/wB (ONE barrier per tile), depth-4 register
// ring (8 loads in flight per wave, fully static slots).
// Plain stores (NT measured to amplify HBM writes 1.5-2.6x).

constexpr int   T_LEN   = 8192;
constexpr int   THREADS = 256;
constexpr int   V       = 4;
constexpr int   TILE    = THREADS * V;    // 1024
constexpr int   NT      = T_LEN / TILE;   // 8 tiles per row/block
constexpr int   NWAVES  = THREADS / 64;   // 4
constexpr float KCOEF   = 0.5f;           // E_MOD / ETA

typedef float f32x4 __attribute__((ext_vector_type(4)));

__global__ __launch_bounds__(THREADS) void maxwell_scan_kernel(
    const float* __restrict__ eps, const float* __restrict__ dtv,
    float* __restrict__ out)
{
    const int tid  = threadIdx.x;
    const int lane = tid & 63;
    const int wid  = tid >> 6;

    __shared__ float wA[2][NWAVES], wB[2][NWAVES];

    const size_t base = (size_t)blockIdx.x * T_LEN + (size_t)tid * V;
    const float* ep = eps + base;
    const float* dp = dtv + base;
    float*       op = out + base;

    // ---- Depth-4 register ring: tiles 0..3 issued up front (8 dense loads).
    f32x4 re0 = *(const f32x4*)(ep);
    f32x4 rd0 = *(const f32x4*)(dp);
    f32x4 re1 = *(const f32x4*)(ep + TILE);
    f32x4 rd1 = *(const f32x4*)(dp + TILE);
    f32x4 re2 = *(const f32x4*)(ep + 2 * TILE);
    f32x4 rd2 = *(const f32x4*)(dp + 2 * TILE);
    f32x4 re3 = *(const f32x4*)(ep + 3 * TILE);
    f32x4 rd3 = *(const f32x4*)(dp + 3 * TILE);

    float gamma = 0.0f;

    // One macro instance per tile -> everything statically indexed.
    // T: tile index. RE/RD: ring slot (slot = T & 3). P: parity (T & 1).
    #define STEP(T, RE, RD, P)                                                \
    do {                                                                      \
        f32x4 E = RE;                                                         \
        f32x4 H = RD * KCOEF;                                                 \
        if ((T) + 4 < NT) {  /* refill this slot with tile T+4 */             \
            RE = *(const f32x4*)(ep + ((T) + 4) * TILE);                      \
            RD = *(const f32x4*)(dp + ((T) + 4) * TILE);                      \
        }                                                                     \
        /* compose 4 elems: gamma_out = A*gamma_in + B */                     \
        float A = 1.0f, Bc = 0.0f;                                            \
        _Pragma("unroll")                                                     \
        for (int j = 0; j < 4; ++j) {                                         \
            float a = 1.0f - H[j];                                            \
            Bc = a * Bc + H[j] * E[j];                                        \
            A *= a;                                                           \
        }                                                                     \
        /* inclusive wave scan under composition */                           \
        float sa = A, sb = Bc;                                                \
        _Pragma("unroll")                                                     \
        for (int off = 1; off < 64; off <<= 1) {                              \
            float pa = __shfl_up(sa, off, 64);                                \
            float pb = __shfl_up(sb, off, 64);                                \
            if (lane >= off) { sb = sa * pb + sb; sa = sa * pa; }             \
        }                                                                     \
        if (lane == 63) { wA[P][wid] = sa; wB[P][wid] = sb; }                 \
        __syncthreads();                                                      \
        float xa = __shfl_up(sa, 1, 64);                                      \
        float xb = __shfl_up(sb, 1, 64);                                      \
        if (lane == 0) { xa = 1.0f; xb = 0.0f; }                              \
        float pfa = 1.0f, pfb = 0.0f, ta = 1.0f, tb = 0.0f;                   \
        _Pragma("unroll")                                                     \
        for (int w = 0; w < NWAVES; ++w) {                                    \
            float a = wA[P][w], bb = wB[P][w];                                \
            if (w < wid) { pfb = a * pfb + bb; pfa *= a; }                    \
            tb = a * tb + bb;                                                 \
            ta *= a;                                                          \
        }                                                                     \
        float g = (xa * pfa) * gamma + (xa * pfb + xb);                       \
        f32x4 sg;                                                             \
        _Pragma("unroll")                                                     \
        for (int j = 0; j < 4; ++j) {                                         \
            sg[j] = 2.5f * E[j] - g;        /* E_INF*e + E*(e - g) */         \
            g = g + H[j] * (E[j] - g);      /* g += dt*k*(e - g)   */         \
        }                                                                     \
        *(f32x4*)(op + (T) * TILE) = sg;    /* dense full-line store */       \
        gamma = ta * gamma + tb;                                              \
    } while (0)

    STEP(0, re0, rd0, 0);
    STEP(1, re1, rd1, 1);
    STEP(2, re2, rd2, 0);
    STEP(3, re3, rd3, 1);
    STEP(4, re0, rd0, 0);
    STEP(5, re1, rd1, 1);
    STEP(6, re2, rd2, 0);
    STEP(7, re3, rd3, 1);

    #undef STEP
}

extern "C" void kernel_launch(void* const* d_in, const int* in_sizes, int n_in,
                              void* d_out, int out_size, void* d_ws, size_t ws_size,
                              hipStream_t stream) {
    const float* eps = (const float*)d_in[0];
    const float* dtv = (const float*)d_in[1];
    float* out = (float*)d_out;
    const int B = in_sizes[0] / T_LEN;    // 4096 rows; one row per block
    maxwell_scan_kernel<<<B, THREADS, 0, stream>>>(eps, dtv, out);
}